// Round 6
// baseline (539.114 us; speedup 1.0000x reference)
//
#include <hip/hip_runtime.h>

// NearestNeighborTokenizer: ids = (min_c ||x - c||^2 <= 900) ? argmin_c : -1
// x: [8192, 512] fp32, codes: [16384, 512] fp32, out: [8192] int32
//
// fp16x3 MFMA GEMM: x,c scaled by 16, split into fp16 hi+lo planes,
// pre-swizzled in global memory into MFMA fragment order. dot =
// (hh + hl + lh)/256 in one fp32 acc. score = ||c||^2 - 2*dot.
//
// R11: 32x32x16 + plane-outer MFMA ordering. R9/R10 post-mortem: the
// shape change itself was correct (absmax 0) but regressed 354->468us,
// MfmaUtil 52.7->40.3 with memory counters unchanged -> pure dependency
// stall: the three fp16x3 products were issued back-to-back into the
// SAME accumulator, and 32x32 MFMA (8-cyc issue, long completion) with
// only 2-chain interleave distance starves the pipe. Fix: per ks-half,
// load all 12 fragments then issue three passes of 8 INDEPENDENT MFMAs
// (all accs x hh, then x hl, then x lh) -> same-acc dependents are 8
// MFMAs (~64 issue cyc) apart. Everything else identical to R10.

#define NTOK   8192
#define NCODES 16384
#define DDIM   512
#define NCHUNK 8
#define CHUNK  2048
#define DIST_THR 900.0f

typedef unsigned short u16;
typedef _Float16 half8 __attribute__((ext_vector_type(8)));
typedef float    f32x4  __attribute__((ext_vector_type(4)));
typedef float    f32x16 __attribute__((ext_vector_type(16)));

// ---------------- kernel 1: merged prep -------------------------------------
// blocks [0,2048): convert+swizzle x -> xh/xl
// blocks [2048,6144): convert+swizzle codes -> ch/cl
// blocks [6144,10240): c2[c] = ||codes[c]||^2 (one wave per code)
//
// Swizzle for 32x32x16 fragments. Linear unit index c (8 halfs each):
//   L=c&63, f=(c>>6)&7, kit=(c>>9)&15, tile=c>>13 ; g=f>>1, ks=f&1
//   row = tile*128 + g*32 + (L&31) ; k = kit*32 + ks*16 + (L>>5)*8
// Each (tile,kit) is a contiguous 8KB block = 8 fragments x 1KB in
// exactly the MFMA operand order (lane L <-> row/col base+(L&31),
// k-half L>>5, 8 contiguous k).
__device__ __forceinline__ void conv_body(const float* __restrict__ src,
                                          u16* __restrict__ dh,
                                          u16* __restrict__ dl, int c) {
    int L = c & 63, f = (c >> 6) & 7, kit = (c >> 9) & 15;
    int tile = c >> 13;
    int g = f >> 1, ks = f & 1;
    int row = tile * 128 + g * 32 + (L & 31);
    int k = kit * 32 + ks * 16 + (L >> 5) * 8;
    const float* p = src + (size_t)row * DDIM + k;
    float4 v0 = *(const float4*)p;
    float4 v1 = *(const float4*)(p + 4);
    float vv[8] = {v0.x, v0.y, v0.z, v0.w, v1.x, v1.y, v1.z, v1.w};
    u16 hs[8], ls[8];
    #pragma unroll
    for (int j = 0; j < 8; ++j) {
        float sv = vv[j] * 16.0f;              // scale 16: keeps lo out of denorms
        _Float16 h = (_Float16)sv;
        float hf = (float)h;
        _Float16 l = (_Float16)(sv - hf);
        union { _Float16 f16; u16 u; } uh, ul;
        uh.f16 = h; ul.f16 = l;
        hs[j] = uh.u; ls[j] = ul.u;
    }
    uint4 H, Lo;
    H.x  = hs[0] | ((unsigned)hs[1] << 16); H.y  = hs[2] | ((unsigned)hs[3] << 16);
    H.z  = hs[4] | ((unsigned)hs[5] << 16); H.w  = hs[6] | ((unsigned)hs[7] << 16);
    Lo.x = ls[0] | ((unsigned)ls[1] << 16); Lo.y = ls[2] | ((unsigned)ls[3] << 16);
    Lo.z = ls[4] | ((unsigned)ls[5] << 16); Lo.w = ls[6] | ((unsigned)ls[7] << 16);
    *(uint4*)(dh + (size_t)c * 8) = H;
    *(uint4*)(dl + (size_t)c * 8) = Lo;
}

__global__ __launch_bounds__(256) void nn_prep(const float* __restrict__ x,
                                               const float* __restrict__ codes,
                                               u16* __restrict__ xh, u16* __restrict__ xl,
                                               u16* __restrict__ ch, u16* __restrict__ cl,
                                               float* __restrict__ c2) {
    int b = blockIdx.x;
    if (b < 2048) {
        conv_body(x, xh, xl, b * 256 + threadIdx.x);
    } else if (b < 6144) {
        conv_body(codes, ch, cl, (b - 2048) * 256 + threadIdx.x);
    } else {
        int w = threadIdx.x >> 6;
        int lane = threadIdx.x & 63;
        int c = (b - 6144) * 4 + w;
        const float* p = codes + (size_t)c * DDIM + lane * 8;
        float4 v0 = *(const float4*)p;
        float4 v1 = *(const float4*)(p + 4);
        float s = v0.x*v0.x + v0.y*v0.y + v0.z*v0.z + v0.w*v0.w
                + v1.x*v1.x + v1.y*v1.y + v1.z*v1.z + v1.w*v1.w;
        #pragma unroll
        for (int off = 32; off > 0; off >>= 1) s += __shfl_down(s, off);
        if (lane == 0) c2[c] = s;
    }
}

// ---------------- kernel 2: 32x32 fp16x3 MFMA GEMM + fused argmin -----------
// grid = 32 mtiles * 8 chunks, blockIdx.x = mtile*8 + chunk (chunk<->XCD).
// Block: 512 threads = 8 waves (wm=wave&3 row-quarter, wn=wave>>2 col-half);
// block tile 256 rows x 256 cols per nt (nt=0..7 over CHUNK=2048).
// Wave tile 64x128 = 2x4 tiles of 32x32. LDS: 2 x 64KB ping-pong
// [Ah 16K|Al 16K|Bh 16K|Bl 16K] + 4KB running-min table at 128K.
__global__ __launch_bounds__(512, 2) void nn_gemm(const u16* __restrict__ xh,
                                                  const u16* __restrict__ xl,
                                                  const u16* __restrict__ chh,
                                                  const u16* __restrict__ cll,
                                                  const float* __restrict__ c2,
                                                  float* __restrict__ pmin,
                                                  int* __restrict__ pid) {
    __shared__ __align__(16) char smem[139264];
    const int tid = threadIdx.x;
    const int lane = tid & 63;
    const int wave = tid >> 6;          // 0..7
    const int wm = wave & 3;            // 64-row quarter
    const int wn = wave >> 2;           // 128-col half
    const int mtile = blockIdx.x >> 3;  // 0..31
    const int chunk = blockIdx.x & 7;   // 0..7
    const int m0 = mtile * 256;
    char* tb = smem + 131072;           // 512 x int2 running (val,id) table

    // init running-min table (rows x wn-half); covered by it=0 top barrier
    if (tid < 512) {
        int2 e; e.x = __float_as_int(3.4e38f); e.y = 0;
        *(int2*)(tb + tid * 8) = e;
    }

    // wave-static staging role: plane = wave>>1 (0 Ah,1 Al,2 Bh,3 Bl),
    // tsub = wave&1 selects which 128-row/col subtile of the 256-tile.
    const int plane = wave >> 1;
    const int tsub  = wave & 1;
    const bool isA = (plane < 2);
    const u16* gbase;
    if (plane == 0)      gbase = xh  + ((size_t)(mtile * 2 + tsub) * 16) * 4096;
    else if (plane == 1) gbase = xl  + ((size_t)(mtile * 2 + tsub) * 16) * 4096;
    else if (plane == 2) gbase = chh + ((size_t)(chunk * 16 + tsub) * 16) * 4096;
    else                 gbase = cll + ((size_t)(chunk * 16 + tsub) * 16) * 4096;
    gbase += lane * 8;
    // LDS dst region for this wave: plane p at p*16KB, subtile at tsub*8KB
    const int ldsoff = wave * 8192;     // == plane*16384 + tsub*8192

    f32x16 acc[2][4];
    #pragma unroll
    for (int i = 0; i < 2; ++i)
        #pragma unroll
        for (int j = 0; j < 4; ++j) acc[i][j] = (f32x16)0.0f;

    // stage iteration it2 = nt*16 + kit into buffer (it2&1)
    auto stage = [&](int it2) {
        int kit2 = it2 & 15, nt2 = it2 >> 4;
        size_t off = (size_t)(isA ? kit2 : nt2 * 32 + kit2) * 4096;
        const u16* src = gbase + off;
        char* dst = smem + (size_t)(it2 & 1) * 65536 + ldsoff;
        #pragma unroll
        for (int s = 0; s < 8; ++s)
            __builtin_amdgcn_global_load_lds(
                (const __attribute__((address_space(1))) void*)(src + s * 512),
                (__attribute__((address_space(3))) void*)(dst + s * 1024),
                16, 0, 0);
    };

    stage(0);
    for (int it = 0; it < 128; ++it) {
        if (it < 127) {
            stage(it + 1);
            // wait only for LAST iteration's 8 loads; this iteration's 8
            // stay in flight across the barrier (counted vmcnt).
            asm volatile("s_waitcnt vmcnt(8)\n\ts_barrier" ::: "memory");
        } else {
            asm volatile("s_waitcnt vmcnt(0)\n\ts_barrier" ::: "memory");
        }

        const char* cur = smem + (size_t)(it & 1) * 65536;

        #pragma unroll
        for (int ks = 0; ks < 2; ++ks) {
            // load ALL fragments for this k-half: 4 A + 8 B ds_read_b128
            half8 ah[2], al[2], bh[4], bl[4];
            #pragma unroll
            for (int i = 0; i < 2; ++i) {
                int gg = wm * 2 + i;            // A 32-row group (0..7)
                int aoff = (gg >> 2) * 8192 + ((gg & 3) * 2 + ks) * 1024 + lane * 16;
                ah[i] = *(const half8*)(cur +         aoff);
                al[i] = *(const half8*)(cur + 16384 + aoff);
            }
            #pragma unroll
            for (int j = 0; j < 4; ++j) {
                int cg = wn * 4 + j;            // B 32-col group (0..7)
                int boff = 32768 + (cg >> 2) * 8192 + ((cg & 3) * 2 + ks) * 1024 + lane * 16;
                bh[j] = *(const half8*)(cur +         boff);
                bl[j] = *(const half8*)(cur + 16384 + boff);
            }
            // plane-outer passes: 8 independent MFMAs per pass; same-acc
            // dependents are 8 MFMAs (~64 issue cyc) apart.
            #pragma unroll
            for (int j = 0; j < 4; ++j)
                #pragma unroll
                for (int i = 0; i < 2; ++i)
                    acc[i][j] = __builtin_amdgcn_mfma_f32_32x32x16_f16(ah[i], bh[j], acc[i][j], 0, 0, 0);
            #pragma unroll
            for (int j = 0; j < 4; ++j)
                #pragma unroll
                for (int i = 0; i < 2; ++i)
                    acc[i][j] = __builtin_amdgcn_mfma_f32_32x32x16_f16(ah[i], bl[j], acc[i][j], 0, 0, 0);
            #pragma unroll
            for (int j = 0; j < 4; ++j)
                #pragma unroll
                for (int i = 0; i < 2; ++i)
                    acc[i][j] = __builtin_amdgcn_mfma_f32_32x32x16_f16(al[i], bh[j], acc[i][j], 0, 0, 0);
        }

        if ((it & 15) == 15) {
            // epilogue for nt: score = ||c||^2 - acc/128 (acc = 256 * x.c).
            // slot s = i*16 + r -> local row wm*64 + (s>>4)*32 + (s&3)
            //   + 8*((s>>2)&3) + 4*(lane>>5); col of candidate = j*32+(lane&31).
            int nt = it >> 4;
            float mvs[32]; int mis[32];
            #pragma unroll
            for (int s = 0; s < 32; ++s) { mvs[s] = 3.4e38f; mis[s] = 0; }
            #pragma unroll
            for (int j = 0; j < 4; ++j) {
                int col = j * 32 + (lane & 31);         // 0..127 within wn-half
                float cv = c2[chunk * CHUNK + nt * 256 + wn * 128 + col];
                #pragma unroll
                for (int i = 0; i < 2; ++i)
                    #pragma unroll
                    for (int r = 0; r < 16; ++r) {
                        float sc = fmaf(acc[i][j][r], -0.0078125f, cv);
                        int slot = i * 16 + r;
                        // cols ascend with j -> '<' keeps lowest id
                        if (sc < mvs[slot]) { mvs[slot] = sc; mis[slot] = col; }
                    }
            }
            // reduce across the 32 col-lanes of each half (bit5 preserved)
            #pragma unroll
            for (int off = 1; off < 32; off <<= 1) {
                #pragma unroll
                for (int s = 0; s < 32; ++s) {
                    float ov = __shfl_xor(mvs[s], off);
                    int   oi = __shfl_xor(mis[s], off);
                    if (ov < mvs[s] || (ov == mvs[s] && oi < mis[s])) { mvs[s] = ov; mis[s] = oi; }
                }
            }
            // single-owner running update: wave (wm,wn) owns rows wm*64..+63
            // in table column wn; lanes 0 and 32 cover disjoint row sets.
            if ((lane & 31) == 0) {
                #pragma unroll
                for (int s = 0; s < 32; ++s) {
                    int row = wm * 64 + (s >> 4) * 32 + (s & 3) + ((s >> 2) & 3) * 8 + (lane >> 5) * 4;
                    int2* e = (int2*)(tb + (wn * 256 + row) * 8);
                    float bv = __int_as_float(e->x);
                    if (mvs[s] < bv) {  // nt ascends -> strict '<' keeps first id
                        int2 w;
                        w.x = __float_as_int(mvs[s]);
                        w.y = chunk * CHUNK + nt * 256 + wn * 128 + mis[s];
                        *e = w;
                    }
                }
            }
            #pragma unroll
            for (int i = 0; i < 2; ++i)
                #pragma unroll
                for (int j = 0; j < 4; ++j) acc[i][j] = (f32x16)0.0f;
        }
        // release barrier: all waves done reading `cur` before it is
        // re-staged at the top of the next iteration.
        asm volatile("s_barrier" ::: "memory");
    }

    __syncthreads();
    if (tid < 256) {
        int2 e0 = *(const int2*)(tb + tid * 8);
        int2 e1 = *(const int2*)(tb + (256 + tid) * 8);
        float v0 = __int_as_float(e0.x), v1 = __int_as_float(e1.x);
        float bv = v0; int bi = e0.y;
        if (v1 < bv || (v1 == bv && e1.y < bi)) { bv = v1; bi = e1.y; }
        pmin[(size_t)(m0 + tid) * NCHUNK + chunk] = bv;
        pid [(size_t)(m0 + tid) * NCHUNK + chunk] = bi;
    }
}

// ---------------- kernel 3: finalize (one wave per token) -------------------
__global__ __launch_bounds__(256) void nn_fin(const float* __restrict__ x,
                                              const float* __restrict__ pmin,
                                              const int* __restrict__ pid,
                                              int* __restrict__ out) {
    int w = threadIdx.x >> 6;
    int lane = threadIdx.x & 63;
    int t = blockIdx.x * 4 + w;
    const float* p = x + (size_t)t * DDIM + lane * 8;
    float4 v0 = *(const float4*)p;
    float4 v1 = *(const float4*)(p + 4);
    float s = v0.x*v0.x + v0.y*v0.y + v0.z*v0.z + v0.w*v0.w
            + v1.x*v1.x + v1.y*v1.y + v1.z*v1.z + v1.w*v1.w;
    #pragma unroll
    for (int off = 32; off > 0; off >>= 1) s += __shfl_down(s, off);
    if (lane == 0) {
        const float* pm = pmin + (size_t)t * NCHUNK;
        const int*   pi = pid  + (size_t)t * NCHUNK;
        float bv = pm[0]; int bi = pi[0];
        #pragma unroll
        for (int c = 1; c < NCHUNK; ++c) {
            float v = pm[c]; int id = pi[c];
            if (v < bv || (v == bv && id < bi)) { bv = v; bi = id; }
        }
        float mind = s + bv;   // ||x||^2 + min(||c||^2 - 2 x.c)
        out[t] = (mind <= DIST_THR) ? bi : -1;
    }
}

extern "C" void kernel_launch(void* const* d_in, const int* in_sizes, int n_in,
                              void* d_out, int out_size, void* d_ws, size_t ws_size,
                              hipStream_t stream) {
    const float* x     = (const float*)d_in[0];
    const float* codes = (const float*)d_in[1];
    int* out = (int*)d_out;

    // workspace layout (bytes):
    //  xh 8MB | xl 8MB | ch 16MB | cl 16MB | c2 64KB | pmin 256KB | pid 256KB
    char* ws = (char*)d_ws;
    u16*   xh   = (u16*)(ws);
    u16*   xl   = (u16*)(ws + 8388608);
    u16*   chh  = (u16*)(ws + 16777216);
    u16*   cll  = (u16*)(ws + 33554432);
    float* c2   = (float*)(ws + 50331648);
    float* pmin = (float*)(ws + 50397184);
    int*   pid  = (int*)  (ws + 50659328);

    nn_prep<<<10240, 256, 0, stream>>>(x, codes, xh, xl, chh, cll, c2);
    nn_gemm<<<32 * NCHUNK, 512, 0, stream>>>(xh, xl, chh, cll, c2, pmin, pid);
    nn_fin<<<NTOK / 4, 256, 0, stream>>>(x, pmin, pid, out);
}

// Round 7
// 386.796 us; speedup vs baseline: 1.3938x; 1.3938x over previous
//
#include <hip/hip_runtime.h>

// NearestNeighborTokenizer: ids = (min_c ||x - c||^2 <= 900) ? argmin_c : -1
// x: [8192, 512] fp32, codes: [16384, 512] fp32, out: [8192] int32
//
// fp16x3 MFMA GEMM: x,c scaled by 16, split into fp16 hi+lo planes,
// pre-swizzled in global memory into MFMA fragment order. dot =
// (hh + hl + lh)/256 in one fp32 acc. score = ||c||^2 - 2*dot.
//
// R12: back to the R5 16x16 base (32x32 path refuted: R10==R11 478us,
// compiler normalizes MFMA order; R5=354us stands). Two changes:
// (1) depth-2 B-fragment prefetch: explicit 2-buffer rotation, B(j+2)
//     issued right after MFMA cluster j (+sched_barrier pin) -> ~116cyc
//     runway vs ~120cyc loaded ds_read latency (compiler's default
//     lookahead-1 gives only ~58cyc -> correlated per-j lgkm stalls).
// (2) single barrier per iteration: vmcnt(0)+s_barrier at body TOP
//     (drains stage(it) issued a full iteration ago -> free wait);
//     stage(it+1) issued after the barrier. Race-audit: each wave's
//     old-buffer ds_reads complete before its last MFMA lgkm wait,
//     hence before barrier entry; stage writes opposite parity only.

#define NTOK   8192
#define NCODES 16384
#define DDIM   512
#define NCHUNK 8
#define CHUNK  2048
#define DIST_THR 900.0f

typedef unsigned short u16;
typedef _Float16 half8 __attribute__((ext_vector_type(8)));
typedef float    f32x4 __attribute__((ext_vector_type(4)));

// ---------------- kernel 1: merged prep -------------------------------------
// blocks [0,2048): convert+swizzle x -> xh/xl
// blocks [2048,6144): convert+swizzle codes -> ch/cl
// blocks [6144,10240): c2[c] = ||codes[c]||^2 (one wave per code)
//
// Swizzle: linear index c (8 halfs each):
//   r=c&15, q=(c>>4)&3, g=(c>>6)&7, kit=(c>>9)&15, tile=c>>13
//   row = tile*128 + g*16 + r ; k = kit*32 + q*8
// Each (tile,kit) is a contiguous 8KB block in exactly the LDS fragment
// layout the GEMM wants (lane L <-> row base+(L&15), k-quad L>>4).
__device__ __forceinline__ void conv_body(const float* __restrict__ src,
                                          u16* __restrict__ dh,
                                          u16* __restrict__ dl, int c) {
    int r = c & 15, q = (c >> 4) & 3, g = (c >> 6) & 7, kit = (c >> 9) & 15;
    int tile = c >> 13;
    int row = tile * 128 + g * 16 + r;
    int k = kit * 32 + q * 8;
    const float* p = src + (size_t)row * DDIM + k;
    float4 v0 = *(const float4*)p;
    float4 v1 = *(const float4*)(p + 4);
    float vv[8] = {v0.x, v0.y, v0.z, v0.w, v1.x, v1.y, v1.z, v1.w};
    u16 hs[8], ls[8];
    #pragma unroll
    for (int j = 0; j < 8; ++j) {
        float sv = vv[j] * 16.0f;              // scale 16: keeps lo out of denorms
        _Float16 h = (_Float16)sv;
        float hf = (float)h;
        _Float16 l = (_Float16)(sv - hf);
        union { _Float16 f; u16 u; } uh, ul;
        uh.f = h; ul.f = l;
        hs[j] = uh.u; ls[j] = ul.u;
    }
    uint4 H, L;
    H.x = hs[0] | ((unsigned)hs[1] << 16); H.y = hs[2] | ((unsigned)hs[3] << 16);
    H.z = hs[4] | ((unsigned)hs[5] << 16); H.w = hs[6] | ((unsigned)hs[7] << 16);
    L.x = ls[0] | ((unsigned)ls[1] << 16); L.y = ls[2] | ((unsigned)ls[3] << 16);
    L.z = ls[4] | ((unsigned)ls[5] << 16); L.w = ls[6] | ((unsigned)ls[7] << 16);
    *(uint4*)(dh + (size_t)c * 8) = H;
    *(uint4*)(dl + (size_t)c * 8) = L;
}

__global__ __launch_bounds__(256) void nn_prep(const float* __restrict__ x,
                                               const float* __restrict__ codes,
                                               u16* __restrict__ xh, u16* __restrict__ xl,
                                               u16* __restrict__ ch, u16* __restrict__ cl,
                                               float* __restrict__ c2) {
    int b = blockIdx.x;
    if (b < 2048) {
        conv_body(x, xh, xl, b * 256 + threadIdx.x);
    } else if (b < 6144) {
        conv_body(codes, ch, cl, (b - 2048) * 256 + threadIdx.x);
    } else {
        int w = threadIdx.x >> 6;
        int lane = threadIdx.x & 63;
        int c = (b - 6144) * 4 + w;
        const float* p = codes + (size_t)c * DDIM + lane * 8;
        float4 v0 = *(const float4*)p;
        float4 v1 = *(const float4*)(p + 4);
        float s = v0.x*v0.x + v0.y*v0.y + v0.z*v0.z + v0.w*v0.w
                + v1.x*v1.x + v1.y*v1.y + v1.z*v1.z + v1.w*v1.w;
        #pragma unroll
        for (int off = 32; off > 0; off >>= 1) s += __shfl_down(s, off);
        if (lane == 0) c2[c] = s;
    }
}

// ---------------- kernel 2: pipelined fp16x3 MFMA GEMM + fused argmin -------
// grid = 32 mtiles * 8 chunks, blockIdx.x = mtile*8 + chunk (chunk<->XCD:
// each XCD's 32 co-resident blocks share one 4MB B-set = its L2).
// Block: 512 threads = 8 waves (wm=wave&3 row-quarter, wn=wave>>2 col-half);
// block tile 256 rows x 256 cols per nt (nt=0..7 over CHUNK=2048).
// Wave tile 64x128. LDS: 2 x 64KB ping-pong [Ah 16K|Al 16K|Bh 16K|Bl 16K].
__global__ __launch_bounds__(512, 2) void nn_gemm(const u16* __restrict__ xh,
                                                  const u16* __restrict__ xl,
                                                  const u16* __restrict__ chh,
                                                  const u16* __restrict__ cll,
                                                  const float* __restrict__ c2,
                                                  float* __restrict__ pmin,
                                                  int* __restrict__ pid) {
    __shared__ __align__(16) char smem[131072];
    const int tid = threadIdx.x;
    const int lane = tid & 63;
    const int wave = tid >> 6;          // 0..7
    const int wm = wave & 3;            // 64-row quarter
    const int wn = wave >> 2;           // 128-col half
    const int mtile = blockIdx.x >> 3;  // 0..31
    const int chunk = blockIdx.x & 7;   // 0..7
    const int m0 = mtile * 256;

    // wave-static staging role: plane = wave>>1 (0 Ah,1 Al,2 Bh,3 Bl),
    // tsub = wave&1 selects which 128-row/col subtile of the 256-tile.
    const int plane = wave >> 1;
    const int tsub  = wave & 1;
    const bool isA = (plane < 2);
    const u16* gbase;
    if (plane == 0)      gbase = xh  + ((size_t)(mtile * 2 + tsub) * 16) * 4096;
    else if (plane == 1) gbase = xl  + ((size_t)(mtile * 2 + tsub) * 16) * 4096;
    else if (plane == 2) gbase = chh + ((size_t)(chunk * 16 + tsub) * 16) * 4096;
    else                 gbase = cll + ((size_t)(chunk * 16 + tsub) * 16) * 4096;
    gbase += lane * 8;
    // LDS dst region for this wave: plane p at p*16KB, subtile at tsub*8KB
    const int ldsoff = wave * 8192;     // == plane*16384 + tsub*8192

    float mv[16];
    int   mi[16];
    #pragma unroll
    for (int s = 0; s < 16; ++s) { mv[s] = 3.4e38f; mi[s] = 0; }

    f32x4 acc[4][8];
    #pragma unroll
    for (int i = 0; i < 4; ++i)
        #pragma unroll
        for (int j = 0; j < 8; ++j) acc[i][j] = (f32x4)0.0f;

    // stage iteration it2 = nt*16 + kit into buffer (it2&1)
    auto stage = [&](int it2) {
        int kit2 = it2 & 15, nt2 = it2 >> 4;
        size_t off = (size_t)(isA ? kit2 : nt2 * 32 + kit2) * 4096;
        const u16* src = gbase + off;
        char* dst = smem + (size_t)(it2 & 1) * 65536 + ldsoff;
        #pragma unroll
        for (int s = 0; s < 8; ++s)
            __builtin_amdgcn_global_load_lds(
                (const __attribute__((address_space(1))) void*)(src + s * 512),
                (__attribute__((address_space(3))) void*)(dst + s * 1024),
                16, 0, 0);
    };

    stage(0);
    for (int it = 0; it < 128; ++it) {
        // single barrier per iteration: stage(it) was issued a full body
        // ago -> vmcnt(0) is ~free. All waves' reads of buf[(it+1)&1]
        // finished in body(it-1) (their last MFMA lgkm wait covers them),
        // so stage(it+1) issued below cannot race.
        asm volatile("s_waitcnt vmcnt(0)\n\ts_barrier" ::: "memory");
        const char* cur = smem + (size_t)(it & 1) * 65536;
        if (it < 127) stage(it + 1);

        // prologue reads: B(0),B(1) into the 2-slot rotation + 8 A frags
        half8 bbh[2], bbl[2];
        bbh[0] = *(const half8*)(cur + 32768 + (wn * 8 + 0) * 1024 + lane * 16);
        bbl[0] = *(const half8*)(cur + 49152 + (wn * 8 + 0) * 1024 + lane * 16);
        bbh[1] = *(const half8*)(cur + 32768 + (wn * 8 + 1) * 1024 + lane * 16);
        bbl[1] = *(const half8*)(cur + 49152 + (wn * 8 + 1) * 1024 + lane * 16);
        half8 ah[4], al[4];
        #pragma unroll
        for (int i = 0; i < 4; ++i) {
            int g = wm * 4 + i;                 // A group (16 rows each)
            ah[i] = *(const half8*)(cur +         g * 1024 + lane * 16);
            al[i] = *(const half8*)(cur + 16384 + g * 1024 + lane * 16);
        }

        #pragma unroll
        for (int j = 0; j < 8; ++j) {           // full unroll: j&1 static
            half8 bh = bbh[j & 1], bl = bbl[j & 1];
            #pragma unroll
            for (int i = 0; i < 4; ++i) {
                acc[i][j] = __builtin_amdgcn_mfma_f32_16x16x32_f16(ah[i], bh, acc[i][j], 0, 0, 0);
                acc[i][j] = __builtin_amdgcn_mfma_f32_16x16x32_f16(ah[i], bl, acc[i][j], 0, 0, 0);
                acc[i][j] = __builtin_amdgcn_mfma_f32_16x16x32_f16(al[i], bh, acc[i][j], 0, 0, 0);
            }
            if (j < 6) {
                // depth-2 prefetch: B(j+2) refills the slot just consumed.
                int g = wn * 8 + j + 2;
                bbh[j & 1] = *(const half8*)(cur + 32768 + g * 1024 + lane * 16);
                bbl[j & 1] = *(const half8*)(cur + 49152 + g * 1024 + lane * 16);
                // pin: next j's MFMAs may not hoist above these reads.
                __builtin_amdgcn_sched_barrier(0);
            }
        }

        if ((it & 15) == 15) {
            // epilogue for nt: score = ||c||^2 - acc/128 (acc = 256 * x.c).
            // candidates arrive in increasing code id -> '<' keeps first.
            int nt = it >> 4;
            #pragma unroll
            for (int j = 0; j < 8; ++j) {
                int ncol = nt * 256 + wn * 128 + j * 16 + (lane & 15);
                int gid = chunk * CHUNK + ncol;
                float cv = c2[gid];
                #pragma unroll
                for (int i = 0; i < 4; ++i)
                    #pragma unroll
                    for (int r = 0; r < 4; ++r) {
                        float s = fmaf(acc[i][j][r], -0.0078125f, cv);
                        int slot = i * 4 + r;
                        if (s < mv[slot]) { mv[slot] = s; mi[slot] = gid; }
                    }
            }
            #pragma unroll
            for (int i = 0; i < 4; ++i)
                #pragma unroll
                for (int j = 0; j < 8; ++j) acc[i][j] = (f32x4)0.0f;
        }
    }

    // shuffle pre-reduce across the 16 col-owner lanes (xor 1,2,4,8 stay
    // within the quad; lane>>4 = row quad is preserved).
    #pragma unroll
    for (int off = 1; off < 16; off <<= 1) {
        #pragma unroll
        for (int s = 0; s < 16; ++s) {
            float ov = __shfl_xor(mv[s], off);
            int   oi = __shfl_xor(mi[s], off);
            if (ov < mv[s] || (ov == mv[s] && oi < mi[s])) { mv[s] = ov; mi[s] = oi; }
        }
    }
    // 2 contributors per row (wn=0,1); 4KB scratch aliases buf0 (all tile
    // reads finished inside the loop; it=127 read buf1 anyway).
    if ((lane & 15) == 0) {
        #pragma unroll
        for (int i = 0; i < 4; ++i)
            #pragma unroll
            for (int r = 0; r < 4; ++r) {
                int row = wm * 64 + i * 16 + (lane >> 4) * 4 + r;
                int2 e;
                e.x = __float_as_int(mv[i * 4 + r]);
                e.y = mi[i * 4 + r];
                *(int2*)(smem + (wn * 256 + row) * 8) = e;
            }
    }
    __syncthreads();
    if (tid < 256) {
        int2 e0 = *(const int2*)(smem + tid * 8);
        int2 e1 = *(const int2*)(smem + (256 + tid) * 8);
        float v0 = __int_as_float(e0.x), v1 = __int_as_float(e1.x);
        float bv = v0; int bi = e0.y;
        if (v1 < bv || (v1 == bv && e1.y < bi)) { bv = v1; bi = e1.y; }
        pmin[(size_t)(m0 + tid) * NCHUNK + chunk] = bv;
        pid [(size_t)(m0 + tid) * NCHUNK + chunk] = bi;
    }
}

// ---------------- kernel 3: finalize (one wave per token) -------------------
__global__ __launch_bounds__(256) void nn_fin(const float* __restrict__ x,
                                              const float* __restrict__ pmin,
                                              const int* __restrict__ pid,
                                              int* __restrict__ out) {
    int w = threadIdx.x >> 6;
    int lane = threadIdx.x & 63;
    int t = blockIdx.x * 4 + w;
    const float* p = x + (size_t)t * DDIM + lane * 8;
    float4 v0 = *(const float4*)p;
    float4 v1 = *(const float4*)(p + 4);
    float s = v0.x*v0.x + v0.y*v0.y + v0.z*v0.z + v0.w*v0.w
            + v1.x*v1.x + v1.y*v1.y + v1.z*v1.z + v1.w*v1.w;
    #pragma unroll
    for (int off = 32; off > 0; off >>= 1) s += __shfl_down(s, off);
    if (lane == 0) {
        const float* pm = pmin + (size_t)t * NCHUNK;
        const int*   pi = pid  + (size_t)t * NCHUNK;
        float bv = pm[0]; int bi = pi[0];
        #pragma unroll
        for (int c = 1; c < NCHUNK; ++c) {
            float v = pm[c]; int id = pi[c];
            if (v < bv || (v == bv && id < bi)) { bv = v; bi = id; }
        }
        float mind = s + bv;   // ||x||^2 + min(||c||^2 - 2 x.c)
        out[t] = (mind <= DIST_THR) ? bi : -1;
    }
}

extern "C" void kernel_launch(void* const* d_in, const int* in_sizes, int n_in,
                              void* d_out, int out_size, void* d_ws, size_t ws_size,
                              hipStream_t stream) {
    const float* x     = (const float*)d_in[0];
    const float* codes = (const float*)d_in[1];
    int* out = (int*)d_out;

    // workspace layout (bytes):
    //  xh 8MB | xl 8MB | ch 16MB | cl 16MB | c2 64KB | pmin 256KB | pid 256KB
    char* ws = (char*)d_ws;
    u16*   xh   = (u16*)(ws);
    u16*   xl   = (u16*)(ws + 8388608);
    u16*   chh  = (u16*)(ws + 16777216);
    u16*   cll  = (u16*)(ws + 33554432);
    float* c2   = (float*)(ws + 50331648);
    float* pmin = (float*)(ws + 50397184);
    int*   pid  = (int*)  (ws + 50659328);

    nn_prep<<<10240, 256, 0, stream>>>(x, codes, xh, xl, chh, cll, c2);
    nn_gemm<<<32 * NCHUNK, 512, 0, stream>>>(xh, xl, chh, cll, c2, pmin, pid);
    nn_fin<<<NTOK / 4, 256, 0, stream>>>(x, pmin, pid, out);
}